// Round 3
// baseline (785.083 us; speedup 1.0000x reference)
//
#include <hip/hip_runtime.h>

// IsoMaxPlusLossFirstPart: logits[b,k,h,w] = -|scale| * || xn(b,:,h,w) - pn(k,:) ||
// Round 3: occupancy + structural prefetch. Previous rounds were stuck at ~185us
// (2x HBM floor) because 4 pix/thread caps the grid at 2 waves/SIMD — too little
// phase diversity to cover loaded-HBM latency. Now: 2 pixels/thread (4096 waves,
// 4 waves/SIMD @ <=128 VGPRs) + explicit two-stage register double-buffer so
// 8 global loads are in flight during every FMA block. Prototypes stay in the
// wave-uniform SMEM path (s_load) via a d_ws pre-normalization kernel.

typedef float f2 __attribute__((ext_vector_type(2)));
typedef float f4 __attribute__((ext_vector_type(4)));

namespace {
constexpr int kC     = 256;
constexpr int kK     = 19;
constexpr int kKP    = 20;          // padded row: 80 B
constexpr int kHW    = 128 * 256;   // 32768
constexpr int kBlock = 256;
constexpr int kPix   = 2;           // pixels per thread (float2 along w)
constexpr int kU     = 8;           // channels per stage
}

// ---- pre-kernel: normalize prototypes into d_ws ----
__global__ void proto_norm_kernel(const float* __restrict__ proto,
                                  float* __restrict__ pn,
                                  float* __restrict__ pp)
{
    const int tid  = threadIdx.x;
    const int lane = tid & 63;
    const int wv   = tid >> 6;
    for (int k = wv; k < kK; k += 4) {
        float v[4];
        float ss = 0.f;
        #pragma unroll
        for (int j = 0; j < 4; ++j) {
            v[j] = proto[k * kC + j * 64 + lane];
            ss = fmaf(v[j], v[j], ss);
        }
        #pragma unroll
        for (int m = 1; m < 64; m <<= 1)
            ss += __shfl_xor(ss, m, 64);
        const float inv = 1.0f / fmaxf(sqrtf(ss), 1e-12f);
        #pragma unroll
        for (int j = 0; j < 4; ++j)
            pn[(j * 64 + lane) * kKP + k] = v[j] * inv;
        if (lane == 0) pp[k] = ss * inv * inv;
    }
    if (tid < kC) pn[tid * kKP + kK] = 0.f;   // zero pad column
}

// ---- main kernel ----
__global__ __launch_bounds__(kBlock, 4)
void isomax_main(const float* __restrict__ feat,
                 const float* __restrict__ pn,
                 const float* __restrict__ pp,
                 const float* __restrict__ dscale,
                 float* __restrict__ out)
{
    const int tid  = threadIdx.x;
    const int gpix = (blockIdx.x * kBlock + tid) * kPix;
    const int b    = gpix >> 15;          // / kHW
    const int hw   = gpix & (kHW - 1);    // % kHW
    const float* fp = feat + (size_t)b * kC * kHW + hw;

    float xx[kPix] = {0.f, 0.f};
    f2 dot[kK];
    #pragma unroll
    for (int k = 0; k < kK; ++k) dot[k] = (f2)(0.f);

    f2 bufA[kU], bufB[kU];

    // prologue: channels 0..7 into A
    #pragma unroll
    for (int u = 0; u < kU; ++u)
        bufA[u] = __builtin_nontemporal_load((const f2*)(fp + (size_t)u * kHW));

    for (int cc = 0; cc < kC; cc += 2 * kU) {
        // issue loads for channels cc+8..cc+15 into B (covers compute A)
        #pragma unroll
        for (int u = 0; u < kU; ++u)
            bufB[u] = __builtin_nontemporal_load(
                          (const f2*)(fp + (size_t)(cc + kU + u) * kHW));
        // compute on A (channels cc..cc+7)
        #pragma unroll
        for (int u = 0; u < kU; ++u) {
            const int c = cc + u;
            const f4* __restrict__ prow = (const f4*)(pn + (size_t)c * kKP);
            f4 P[5];
            #pragma unroll
            for (int q = 0; q < 5; ++q) P[q] = prow[q];   // uniform -> s_load
            const float* p = (const float*)P;
            xx[0] = fmaf(bufA[u].x, bufA[u].x, xx[0]);
            xx[1] = fmaf(bufA[u].y, bufA[u].y, xx[1]);
            #pragma unroll
            for (int k = 0; k < kK; ++k) {
                dot[k].x = fmaf(p[k], bufA[u].x, dot[k].x);
                dot[k].y = fmaf(p[k], bufA[u].y, dot[k].y);
            }
        }
        // issue loads for channels cc+16..cc+23 into A (covers compute B)
        if (cc + 2 * kU < kC) {
            #pragma unroll
            for (int u = 0; u < kU; ++u)
                bufA[u] = __builtin_nontemporal_load(
                              (const f2*)(fp + (size_t)(cc + 2 * kU + u) * kHW));
        }
        // compute on B (channels cc+8..cc+15)
        #pragma unroll
        for (int u = 0; u < kU; ++u) {
            const int c = cc + kU + u;
            const f4* __restrict__ prow = (const f4*)(pn + (size_t)c * kKP);
            f4 P[5];
            #pragma unroll
            for (int q = 0; q < 5; ++q) P[q] = prow[q];
            const float* p = (const float*)P;
            xx[0] = fmaf(bufB[u].x, bufB[u].x, xx[0]);
            xx[1] = fmaf(bufB[u].y, bufB[u].y, xx[1]);
            #pragma unroll
            for (int k = 0; k < kK; ++k) {
                dot[k].x = fmaf(p[k], bufB[u].x, dot[k].x);
                dot[k].y = fmaf(p[k], bufB[u].y, dot[k].y);
            }
        }
    }

    // ---- epilogue ----
    float inv[kPix], xnsq[kPix];
    #pragma unroll
    for (int j = 0; j < kPix; ++j) {
        inv[j]  = 1.0f / fmaxf(sqrtf(xx[j]), 1e-12f);
        xnsq[j] = xx[j] * inv[j] * inv[j];
    }
    const float sc = fabsf(dscale[0]);

    float* op = out + (size_t)b * kK * kHW + hw;
    #pragma unroll
    for (int k = 0; k < kK; ++k) {
        const float ppk = pp[k];            // uniform -> s_load
        f2 o;
        o.x = -sc * sqrtf(fmaxf(xnsq[0] + ppk - 2.0f * dot[k].x * inv[0], 0.f));
        o.y = -sc * sqrtf(fmaxf(xnsq[1] + ppk - 2.0f * dot[k].y * inv[1], 0.f));
        __builtin_nontemporal_store(o, (f2*)(op + (size_t)k * kHW));
    }
}

extern "C" void kernel_launch(void* const* d_in, const int* in_sizes, int n_in,
                              void* d_out, int out_size, void* d_ws, size_t ws_size,
                              hipStream_t stream) {
    const float* feat   = (const float*)d_in[0];
    const float* proto  = (const float*)d_in[1];
    const float* dscale = (const float*)d_in[2];
    float* out = (float*)d_out;

    float* pn = (float*)d_ws;               // [256][20]
    float* pp = pn + kC * kKP;              // [19]

    proto_norm_kernel<<<dim3(1), dim3(256), 0, stream>>>(proto, pn, pp);

    const int npix    = in_sizes[0] / kC;   // 524288
    const int threads = npix / kPix;        // 262144
    isomax_main<<<dim3(threads / kBlock), dim3(kBlock), 0, stream>>>(
        feat, pn, pp, dscale, out);
}